// Round 3
// baseline (562.364 us; speedup 1.0000x reference)
//
#include <hip/hip_runtime.h>

typedef short short8 __attribute__((ext_vector_type(8)));
typedef float floatx4 __attribute__((ext_vector_type(4)));

#define BB   8
#define CIN  16
#define COUT 32
#define DD   64
#define NUM_W (CIN * COUT * 27)   // 13824
#define NUM_P (NUM_W + COUT)      // 13856
#define KPAD  448                 // 28 taps * 16 ci (tap 27 = zeros)

// ws layout (floats): [0,64) h1 (8x8); [64,320) bias (8x32);
// [320, ...) A_bf16 as shorts: 8*32*448 shorts = 229376 B. Total ~231 KB.

__device__ __forceinline__ short f2bf(float f) {
    union { float f; unsigned u; } v; v.f = f;
    unsigned r = v.u + 0x7FFF + ((v.u >> 16) & 1);   // RNE
    return (short)(r >> 16);
}

// pack bf16(lo) | bf16(hi)<<16, both RNE — identical numerics to f2bf
__device__ __forceinline__ unsigned pack2bf(float lo, float hi) {
    union { float f; unsigned u; } a, b; a.f = lo; b.f = hi;
    unsigned ra = a.u + 0x7FFF + ((a.u >> 16) & 1);
    unsigned rb = b.u + 0x7FFF + ((b.u >> 16) & 1);
    return (ra >> 16) | (rb & 0xFFFF0000u);
}

// LDS bank-conflict swizzle: XOR bits 4-6 of the byte address with bits 7-9.
// Bijective per 128B window (buffer = 38016 B = 297 * 128B exactly).
// Preserves 16B alignment for b128 ops and 4B alignment for b32 writes.
__device__ __forceinline__ int swz(int byte) {
    return byte ^ (((byte >> 7) & 7) << 4);
}

__global__ void hyper_kernel(const float* __restrict__ features,
                             const float* __restrict__ fc0_w,
                             const float* __restrict__ fc0_b,
                             const float* __restrict__ a0,
                             const float* __restrict__ fc1_w,
                             const float* __restrict__ fc1_b,
                             const float* __restrict__ a1,
                             const float* __restrict__ wg_w,
                             const float* __restrict__ wg_b,
                             float* __restrict__ h1out,
                             float* __restrict__ biasout) {
    __shared__ float h0[8][16];
    __shared__ float h1s[8][8];
    const int t = threadIdx.x;  // 256
    if (t < 128) {
        const int b = t >> 4, i = t & 15;
        float s = fc0_b[i];
        #pragma unroll
        for (int j = 0; j < 10; ++j) s += features[b * 10 + j] * fc0_w[i * 10 + j];
        const float a = a0[0];
        h0[b][i] = (s >= 0.f) ? s : a * s;
    }
    __syncthreads();
    if (t < 64) {
        const int b = t >> 3, i = t & 7;
        float s = fc1_b[i];
        #pragma unroll
        for (int j = 0; j < 16; ++j) s += h0[b][j] * fc1_w[i * 16 + j];
        const float a = a1[0];
        const float r = (s >= 0.f) ? s : a * s;
        h1s[b][i] = r;
        h1out[b * 8 + i] = r;
    }
    __syncthreads();
    {   // biases: 256 threads = 8 b x 32 co
        const int b = t >> 5, co = t & 31;
        const int p = NUM_W + co;
        float s = wg_b[p];
        #pragma unroll
        for (int j = 0; j < 8; ++j) s += h1s[b][j] * wg_w[p * 8 + j];
        biasout[b * 32 + co] = s;
    }
}

// A_bf16[b][co][k], k = tap*16 + ci, tap = kd*9+kh*3+kw, zero for tap==27
// Thread map: tap fastest -> adjacent lanes read adjacent wg_w rows (coalesced).
__global__ void wgen_kernel(const float* __restrict__ h1,
                            const float* __restrict__ wg_w,
                            const float* __restrict__ wg_b,
                            short* __restrict__ A) {
    const int b  = blockIdx.y;
    const int id = blockIdx.x * 256 + threadIdx.x;  // [0, 32*16*28)
    const int tap  = id % 28;
    const int rest = id / 28;        // co*16 + ci
    const int ci   = rest & 15;
    const int co   = rest >> 4;
    float val = 0.f;
    if (tap < 27) {
        const int p = co * 432 + ci * 27 + tap;
        float s = wg_b[p];
        #pragma unroll
        for (int j = 0; j < 8; ++j) s += h1[b * 8 + j] * wg_w[p * 8 + j];
        val = s;
    }
    A[(b * 32 + co) * KPAD + tap * 16 + ci] = f2bf(val);
}

// Implicit-GEMM conv via MFMA 16x16x32 bf16 — persistent 8-tile blocks.
// Block = 256 thr = 4 waves; fixes (b, d, h-half); loops 8 tiles over h0.
// A (28 KB/sample) preloaded to VGPRs ONCE, reused across all 8 tiles.
// LDS x-patch: [dz 3][hz 6][wz 66][ci 16] bf16, XOR-swizzled (see swz()).
__global__ __launch_bounds__(256, 2) void conv_mfma_kernel(
        const float* __restrict__ x,
        const short* __restrict__ A,
        const float* __restrict__ bias,
        float* __restrict__ out) {
    __shared__ uint4 xs4[2376];            // 38016 B = 3*6*66*16 bf16
    char* xsb = (char*)xs4;

    const int t    = threadIdx.x;
    const int lane = t & 63;
    const int wave = t >> 6;
    const int n16  = lane & 15;
    const int q    = lane >> 4;

    // XCD-aware chunking: 1024 blocks, 8 XCDs, 128 blocks/XCD = exactly one
    // sample b per XCD -> its 28 KB A + x halo rows stay L2-hot.
    const int lin   = blockIdx.x;                    // 0..1023
    const int o     = (lin & 7) * 128 + (lin >> 3);  // bijective
    const int b     = o >> 7;                        // 0..7
    const int rest  = o & 127;
    const int d     = rest >> 1;                     // 0..63
    const int hbase = (rest & 1) * 32;               // h0 = hbase + it*4

    // ---- preload ALL A-fragments once (112 VGPRs, live across tile loop) ----
    short8 afrag[14][2];
    const short* Ab = A + (size_t)(b * 32) * KPAD;
    #pragma unroll
    for (int c = 0; c < 14; ++c)
        #pragma unroll
        for (int mt = 0; mt < 2; ++mt)
            afrag[c][mt] = *(const short8*)(Ab + (mt * 16 + n16) * KPAD + c * 32 + q * 8);

    // ---- zero the w-halo columns (wz=0,65) ONCE; staging never writes them ----
    if (t < 72) {
        const int rowl = t >> 2;                 // 0..17
        const int wz   = ((t >> 1) & 1) * 65;    // 0 or 65
        const int half = t & 1;
        const uint4 z4 = {0u, 0u, 0u, 0u};
        *(uint4*)(xsb + swz((rowl * 66 + wz) * 32 + half * 16)) = z4;
    }

    const float bv0 = bias[b * 32 + n16];
    const float bv1 = bias[b * 32 + 16 + n16];

    // staging thread map: (ci-pair cp, row-half rhalf) wave-uniform rows
    const int tid16 = wave * 4 + q;      // 0..15
    const int cp    = tid16 & 7;         // ci = 2*cp, 2*cp+1
    const int rhalf = tid16 >> 3;        // rows 0..8 / 9..17
    const int w4    = n16 * 4;

    const int ci_base2 = (q & 1) * 16;   // byte offset of ci half
    const int qh       = q >> 1;

    #pragma unroll 1
    for (int it = 0; it < 8; ++it) {
        const int h0 = hbase + it * 4;

        __syncthreads();   // prev tile's LDS reads (or halo-zero) complete

        // ---- stage x -> LDS bf16 (unconditional writes; zeros for OOB rows) ----
        #pragma unroll
        for (int i = 0; i < 9; ++i) {
            const int rowl = rhalf * 9 + i;              // dz*6+hz
            const int dz = rowl / 6, hz = rowl % 6;
            const int zd = d + dz - 1;
            const int zh = h0 + hz - 1;
            float4 v0 = {0.f, 0.f, 0.f, 0.f};
            float4 v1 = {0.f, 0.f, 0.f, 0.f};
            if (zd >= 0 && zd < DD && zh >= 0 && zh < DD) {   // wave-uniform
                const size_t gbase =
                    (((size_t)(b * CIN + 2 * cp) * DD + zd) * DD + zh) * DD + w4;
                v0 = *(const float4*)(x + gbase);
                v1 = *(const float4*)(x + gbase + (size_t)DD * DD * DD);
            }
            const int rb = (rowl * 66 + (w4 + 1)) * 32 + 4 * cp;
            *(unsigned*)(xsb + swz(rb))      = pack2bf(v0.x, v1.x);
            *(unsigned*)(xsb + swz(rb + 32)) = pack2bf(v0.y, v1.y);
            *(unsigned*)(xsb + swz(rb + 64)) = pack2bf(v0.z, v1.z);
            *(unsigned*)(xsb + swz(rb + 96)) = pack2bf(v0.w, v1.w);
        }
        __syncthreads();

        // ---- K-loop: operand-swapped MFMA (x in A slot -> rows = w) ----
        floatx4 acc[2][4];
        #pragma unroll
        for (int mt = 0; mt < 2; ++mt)
            #pragma unroll
            for (int nt = 0; nt < 4; ++nt) acc[mt][nt] = (floatx4){0.f, 0.f, 0.f, 0.f};

        #pragma unroll
        for (int c = 0; c < 14; ++c) {
            int tap = 2 * c + qh;
            if (tap > 26) tap = 26;            // A zero for k>=432, B value irrelevant
            const int kd = tap / 9;
            const int r  = tap - kd * 9;
            const int kh = r / 3;
            const int kw = r - kh * 3;
            const int rowb = ((kd * 6 + wave + kh) * 66 + kw) * 32 + ci_base2;
            #pragma unroll
            for (int nt = 0; nt < 4; ++nt) {
                const short8 xf = *(const short8*)(xsb + swz(rowb + (nt * 16 + n16) * 32));
                acc[0][nt] = __builtin_amdgcn_mfma_f32_16x16x32_bf16(
                                 xf, afrag[c][0], acc[0][nt], 0, 0, 0);
                acc[1][nt] = __builtin_amdgcn_mfma_f32_16x16x32_bf16(
                                 xf, afrag[c][1], acc[1][nt], 0, 0, 0);
            }
        }

        // ---- epilogue: row=w=nt*16+q*4+reg, col=co=mt*16+n16 -> float4 stores ----
        const int hh = h0 + wave;
        #pragma unroll
        for (int mt = 0; mt < 2; ++mt) {
            const float bv = mt ? bv1 : bv0;
            #pragma unroll
            for (int nt = 0; nt < 4; ++nt) {
                floatx4 rr = acc[mt][nt];
                rr[0] += bv; rr[1] += bv; rr[2] += bv; rr[3] += bv;
                *(floatx4*)(out + (((size_t)(b * COUT + mt * 16 + n16) * DD + d) * DD + hh) * DD
                                 + nt * 16 + q * 4) = rr;
            }
        }
    }
}

extern "C" void kernel_launch(void* const* d_in, const int* in_sizes, int n_in,
                              void* d_out, int out_size, void* d_ws, size_t ws_size,
                              hipStream_t stream) {
    const float* x        = (const float*)d_in[0];
    const float* features = (const float*)d_in[1];
    const float* fc0_w    = (const float*)d_in[2];
    const float* fc0_b    = (const float*)d_in[3];
    const float* a0       = (const float*)d_in[4];
    const float* fc1_w    = (const float*)d_in[5];
    const float* fc1_b    = (const float*)d_in[6];
    const float* a1       = (const float*)d_in[7];
    const float* wg_w     = (const float*)d_in[8];
    const float* wg_b     = (const float*)d_in[9];

    float* ws    = (float*)d_ws;
    float* h1    = ws;                // 64 floats
    float* biasp = ws + 64;           // 256 floats
    short* A     = (short*)(ws + 320);  // 8*32*448 shorts

    hyper_kernel<<<1, 256, 0, stream>>>(features, fc0_w, fc0_b, a0,
                                        fc1_w, fc1_b, a1, wg_w, wg_b, h1, biasp);
    wgen_kernel<<<dim3(56, BB), 256, 0, stream>>>(h1, wg_w, wg_b, A);
    conv_mfma_kernel<<<dim3(1024), 256, 0, stream>>>(x, A, biasp, (float*)d_out);
}

// Round 4
// 486.375 us; speedup vs baseline: 1.1562x; 1.1562x over previous
//
#include <hip/hip_runtime.h>

typedef short short8 __attribute__((ext_vector_type(8)));
typedef float floatx4 __attribute__((ext_vector_type(4)));

#define BB   8
#define CIN  16
#define COUT 32
#define DD   64
#define NUM_W (CIN * COUT * 27)   // 13824
#define NUM_P (NUM_W + COUT)      // 13856
#define KPAD  448                 // 28 taps * 16 ci (tap 27 = zeros)

// ws layout (floats): [0,64) h1 (8x8); [64,320) bias (8x32);
// [320, ...) A_bf16 as shorts: 8*32*448 shorts = 229376 B. Total ~231 KB.

__device__ __forceinline__ short f2bf(float f) {
    union { float f; unsigned u; } v; v.f = f;
    unsigned r = v.u + 0x7FFF + ((v.u >> 16) & 1);   // RNE
    return (short)(r >> 16);
}

// pack bf16(lo) | bf16(hi)<<16, both RNE — identical numerics to f2bf
__device__ __forceinline__ unsigned pack2bf(float lo, float hi) {
    union { float f; unsigned u; } a, b; a.f = lo; b.f = hi;
    unsigned ra = a.u + 0x7FFF + ((a.u >> 16) & 1);
    unsigned rb = b.u + 0x7FFF + ((b.u >> 16) & 1);
    return (ra >> 16) | (rb & 0xFFFF0000u);
}

// LDS bank-conflict swizzle for the x-patch: XOR bits 4-6 with bits 7-9.
// Bijective per 128B window (xs = 38016 B = 297 * 128B exactly).
__device__ __forceinline__ int swz(int byte) {
    return byte ^ (((byte >> 7) & 7) << 4);
}

__global__ void hyper_kernel(const float* __restrict__ features,
                             const float* __restrict__ fc0_w,
                             const float* __restrict__ fc0_b,
                             const float* __restrict__ a0,
                             const float* __restrict__ fc1_w,
                             const float* __restrict__ fc1_b,
                             const float* __restrict__ a1,
                             const float* __restrict__ wg_w,
                             const float* __restrict__ wg_b,
                             float* __restrict__ h1out,
                             float* __restrict__ biasout) {
    __shared__ float h0[8][16];
    __shared__ float h1s[8][8];
    const int t = threadIdx.x;  // 256
    if (t < 128) {
        const int b = t >> 4, i = t & 15;
        float s = fc0_b[i];
        #pragma unroll
        for (int j = 0; j < 10; ++j) s += features[b * 10 + j] * fc0_w[i * 10 + j];
        const float a = a0[0];
        h0[b][i] = (s >= 0.f) ? s : a * s;
    }
    __syncthreads();
    if (t < 64) {
        const int b = t >> 3, i = t & 7;
        float s = fc1_b[i];
        #pragma unroll
        for (int j = 0; j < 16; ++j) s += h0[b][j] * fc1_w[i * 16 + j];
        const float a = a1[0];
        const float r = (s >= 0.f) ? s : a * s;
        h1s[b][i] = r;
        h1out[b * 8 + i] = r;
    }
    __syncthreads();
    {   // biases: 256 threads = 8 b x 32 co
        const int b = t >> 5, co = t & 31;
        const int p = NUM_W + co;
        float s = wg_b[p];
        #pragma unroll
        for (int j = 0; j < 8; ++j) s += h1s[b][j] * wg_w[p * 8 + j];
        biasout[b * 32 + co] = s;
    }
}

// A_bf16[b][co][k], k = tap*16 + ci, tap = kd*9+kh*3+kw, zero for tap==27
__global__ void wgen_kernel(const float* __restrict__ h1,
                            const float* __restrict__ wg_w,
                            const float* __restrict__ wg_b,
                            short* __restrict__ A) {
    const int b  = blockIdx.y;
    const int id = blockIdx.x * 256 + threadIdx.x;  // [0, 32*16*28)
    const int tap  = id % 28;
    const int rest = id / 28;        // co*16 + ci
    const int ci   = rest & 15;
    const int co   = rest >> 4;
    float val = 0.f;
    if (tap < 27) {
        const int p = co * 432 + ci * 27 + tap;
        float s = wg_b[p];
        #pragma unroll
        for (int j = 0; j < 8; ++j) s += h1[b * 8 + j] * wg_w[p * 8 + j];
        val = s;
    }
    A[(b * 32 + co) * KPAD + tap * 16 + ci] = f2bf(val);
}

// Implicit-GEMM conv via MFMA 16x16x32 bf16.
// Block = 256 thr = 4 waves; tile = (b, d, h0..h0+3, w 0..63).
// x-patch in LDS: [dz 3][hz 6][wz 66][ci 16] bf16, XOR-swizzled (swz()).
// A chunks 0..12 staged to LDS ONCE per block in a conflict-free layout
// (lane l reads byte l*16 of its 1024B slot-group) -> K-loop has NO global
// loads; chunk 13 (tap 26 + zero tail) kept in 2 regs per thread.
__global__ __launch_bounds__(256, 2) void conv_mfma_kernel(
        const float* __restrict__ x,
        const short* __restrict__ A,
        const float* __restrict__ bias,
        float* __restrict__ out) {
    __shared__ uint4 xs4[2376];            // 38016 B
    __shared__ uint4 als4[1664];           // 26624 B = 26 * 1024B (c 0..12, mt 0..1)
    char* xsb = (char*)xs4;
    char* alb = (char*)als4;

    const int t    = threadIdx.x;
    const int lane = t & 63;
    const int wave = t >> 6;
    const int n16  = lane & 15;
    const int q    = lane >> 4;

    // XCD-aware swizzle (round-2 proven): each XCD owns one sample b.
    const int lin = (blockIdx.z * 64 + blockIdx.y) * 16 + blockIdx.x;  // 0..8191
    const int o   = (lin & 7) * 1024 + (lin >> 3);                     // bijective
    const int h0  = (o & 15) * 4;
    const int d   = (o >> 4) & 63;
    const int b   = o >> 10;

    const short* Ab = A + (size_t)(b * 32) * KPAD;

    // ---- stage A chunks 0..12 -> LDS (26*64 = 1664 uint4 units) ----
    // unit u -> (cm=u>>6 -> c=cm>>1, mt=cm&1; nn=(u>>2)&15; qs=u&3)
    // dest byte = u*16 (linear);  K-loop read: lane(n16,q) -> byte n16*64+q*16.
    #pragma unroll
    for (int i = 0; i < 7; ++i) {
        const int u = t + i * 256;
        if (u < 1664) {
            const int cm = u >> 6;
            const int c  = cm >> 1, mt = cm & 1;
            const int nn = (u >> 2) & 15, qs = u & 3;
            als4[u] = *(const uint4*)(Ab + (mt * 16 + nn) * KPAD + c * 32 + qs * 8);
        }
    }

    // ---- chunk 13 (taps 26,27; k>=432 already zero in A) per-thread regs ----
    short8 af13[2];
    af13[0] = *(const short8*)(Ab + n16 * KPAD + 13 * 32 + q * 8);
    af13[1] = *(const short8*)(Ab + (16 + n16) * KPAD + 13 * 32 + q * 8);

    // ---- zero the w-halo columns (wz=0,65); staging never writes them ----
    if (t < 72) {
        const int rowl = t >> 2;                 // 0..17
        const int wz   = ((t >> 1) & 1) * 65;    // 0 or 65
        const int half = t & 1;
        const uint4 z4 = {0u, 0u, 0u, 0u};
        *(uint4*)(xsb + swz((rowl * 66 + wz) * 32 + half * 16)) = z4;
    }

    const float bv0 = bias[b * 32 + n16];
    const float bv1 = bias[b * 32 + 16 + n16];

    // ---- stage x -> LDS bf16 (unconditional writes; zeros for OOB rows) ----
    const int tid16 = wave * 4 + q;      // 0..15
    const int cp    = tid16 & 7;         // ci = 2*cp, 2*cp+1
    const int rhalf = tid16 >> 3;        // rows 0..8 / 9..17
    const int w4    = n16 * 4;
    #pragma unroll
    for (int i = 0; i < 9; ++i) {
        const int rowl = rhalf * 9 + i;              // dz*6+hz
        const int dz = rowl / 6, hz = rowl % 6;
        const int zd = d + dz - 1;
        const int zh = h0 + hz - 1;
        float4 v0 = {0.f, 0.f, 0.f, 0.f};
        float4 v1 = {0.f, 0.f, 0.f, 0.f};
        if (zd >= 0 && zd < DD && zh >= 0 && zh < DD) {   // wave-uniform
            const size_t gbase =
                (((size_t)(b * CIN + 2 * cp) * DD + zd) * DD + zh) * DD + w4;
            v0 = *(const float4*)(x + gbase);
            v1 = *(const float4*)(x + gbase + (size_t)DD * DD * DD);
        }
        const int rb = (rowl * 66 + (w4 + 1)) * 32 + 4 * cp;
        *(unsigned*)(xsb + swz(rb))      = pack2bf(v0.x, v1.x);
        *(unsigned*)(xsb + swz(rb + 32)) = pack2bf(v0.y, v1.y);
        *(unsigned*)(xsb + swz(rb + 64)) = pack2bf(v0.z, v1.z);
        *(unsigned*)(xsb + swz(rb + 96)) = pack2bf(v0.w, v1.w);
    }
    __syncthreads();

    // ---- K-loop: operand-swapped MFMA (x in A slot, weights in B slot) ----
    floatx4 acc[2][4];
    #pragma unroll
    for (int mt = 0; mt < 2; ++mt)
        #pragma unroll
        for (int nt = 0; nt < 4; ++nt) acc[mt][nt] = (floatx4){0.f, 0.f, 0.f, 0.f};

    const int ci_base2 = (q & 1) * 16;   // byte offset of ci half
    const int qh       = q >> 1;
    const int aoff     = n16 * 64 + q * 16;   // lane's byte in a 1024B slot-group
    #pragma unroll
    for (int c = 0; c < 14; ++c) {
        int tap = 2 * c + qh;
        if (tap > 26) tap = 26;            // A zero for k>=432, x value irrelevant
        const int kd = tap / 9;
        const int r  = tap - kd * 9;
        const int kh = r / 3;
        const int kw = r - kh * 3;
        const int rowb = ((kd * 6 + wave + kh) * 66 + kw) * 32 + ci_base2;
        const short8 a0 = (c < 13) ? *(const short8*)(alb + (c * 2) * 1024 + aoff)
                                   : af13[0];
        const short8 a1 = (c < 13) ? *(const short8*)(alb + (c * 2 + 1) * 1024 + aoff)
                                   : af13[1];
        #pragma unroll
        for (int nt = 0; nt < 4; ++nt) {
            const short8 xf = *(const short8*)(xsb + swz(rowb + (nt * 16 + n16) * 32));
            acc[0][nt] = __builtin_amdgcn_mfma_f32_16x16x32_bf16(
                             xf, a0, acc[0][nt], 0, 0, 0);
            acc[1][nt] = __builtin_amdgcn_mfma_f32_16x16x32_bf16(
                             xf, a1, acc[1][nt], 0, 0, 0);
        }
    }

    // ---- epilogue: row=w=nt*16+q*4+reg, col=co=mt*16+n16 -> float4 stores ----
    const int hh = h0 + wave;
    #pragma unroll
    for (int mt = 0; mt < 2; ++mt) {
        const float bv = mt ? bv1 : bv0;
        #pragma unroll
        for (int nt = 0; nt < 4; ++nt) {
            floatx4 rr = acc[mt][nt];
            rr[0] += bv; rr[1] += bv; rr[2] += bv; rr[3] += bv;
            *(floatx4*)(out + (((size_t)(b * COUT + mt * 16 + n16) * DD + d) * DD + hh) * DD
                             + nt * 16 + q * 4) = rr;
        }
    }
}

extern "C" void kernel_launch(void* const* d_in, const int* in_sizes, int n_in,
                              void* d_out, int out_size, void* d_ws, size_t ws_size,
                              hipStream_t stream) {
    const float* x        = (const float*)d_in[0];
    const float* features = (const float*)d_in[1];
    const float* fc0_w    = (const float*)d_in[2];
    const float* fc0_b    = (const float*)d_in[3];
    const float* a0       = (const float*)d_in[4];
    const float* fc1_w    = (const float*)d_in[5];
    const float* fc1_b    = (const float*)d_in[6];
    const float* a1       = (const float*)d_in[7];
    const float* wg_w     = (const float*)d_in[8];
    const float* wg_b     = (const float*)d_in[9];

    float* ws    = (float*)d_ws;
    float* h1    = ws;                // 64 floats
    float* biasp = ws + 64;           // 256 floats
    short* A     = (short*)(ws + 320);  // 8*32*448 shorts

    hyper_kernel<<<1, 256, 0, stream>>>(features, fc0_w, fc0_b, a0,
                                        fc1_w, fc1_b, a1, wg_w, wg_b, h1, biasp);
    wgen_kernel<<<dim3(56, BB), 256, 0, stream>>>(h1, wg_w, wg_b, A);
    conv_mfma_kernel<<<dim3(16, DD, BB), 256, 0, stream>>>(x, A, biasp, (float*)d_out);
}

// Round 6
// 456.800 us; speedup vs baseline: 1.2311x; 1.0647x over previous
//
#include <hip/hip_runtime.h>

typedef short short8 __attribute__((ext_vector_type(8)));
typedef float floatx4 __attribute__((ext_vector_type(4)));

#define BB   8
#define CIN  16
#define COUT 32
#define DD   64
#define NUM_W (CIN * COUT * 27)   // 13824
#define NUM_P (NUM_W + COUT)      // 13856
#define KPAD  448                 // 28 taps * 16 ci (tap 27 = zeros)

// ws layout (floats): [0,64) h1 (8x8); [64,320) bias (8x32);
// [320, ...) A_bf16 as shorts: 8*32*448 shorts = 229376 B. Total ~231 KB.

__device__ __forceinline__ short f2bf(float f) {
    union { float f; unsigned u; } v; v.f = f;
    unsigned r = v.u + 0x7FFF + ((v.u >> 16) & 1);   // RNE
    return (short)(r >> 16);
}

// pack bf16(lo) | bf16(hi)<<16, both RNE — identical numerics to f2bf
__device__ __forceinline__ unsigned pack2bf(float lo, float hi) {
    union { float f; unsigned u; } a, b; a.f = lo; b.f = hi;
    unsigned ra = a.u + 0x7FFF + ((a.u >> 16) & 1);
    unsigned rb = b.u + 0x7FFF + ((b.u >> 16) & 1);
    return (ra >> 16) | (rb & 0xFFFF0000u);
}

// LDS bank-conflict swizzle for the x-patch: XOR bits 4-6 with bits 7-9.
// Bijective per 128B window (xs = 38016 B = 297 * 128B exactly).
__device__ __forceinline__ int swz(int byte) {
    return byte ^ (((byte >> 7) & 7) << 4);
}

__global__ void hyper_kernel(const float* __restrict__ features,
                             const float* __restrict__ fc0_w,
                             const float* __restrict__ fc0_b,
                             const float* __restrict__ a0,
                             const float* __restrict__ fc1_w,
                             const float* __restrict__ fc1_b,
                             const float* __restrict__ a1,
                             const float* __restrict__ wg_w,
                             const float* __restrict__ wg_b,
                             float* __restrict__ h1out,
                             float* __restrict__ biasout) {
    __shared__ float h0[8][16];
    __shared__ float h1s[8][8];
    const int t = threadIdx.x;  // 256
    if (t < 128) {
        const int b = t >> 4, i = t & 15;
        float s = fc0_b[i];
        #pragma unroll
        for (int j = 0; j < 10; ++j) s += features[b * 10 + j] * fc0_w[i * 10 + j];
        const float a = a0[0];
        h0[b][i] = (s >= 0.f) ? s : a * s;
    }
    __syncthreads();
    if (t < 64) {
        const int b = t >> 3, i = t & 7;
        float s = fc1_b[i];
        #pragma unroll
        for (int j = 0; j < 16; ++j) s += h0[b][j] * fc1_w[i * 16 + j];
        const float a = a1[0];
        const float r = (s >= 0.f) ? s : a * s;
        h1s[b][i] = r;
        h1out[b * 8 + i] = r;
    }
    __syncthreads();
    {   // biases: 256 threads = 8 b x 32 co
        const int b = t >> 5, co = t & 31;
        const int p = NUM_W + co;
        float s = wg_b[p];
        #pragma unroll
        for (int j = 0; j < 8; ++j) s += h1s[b][j] * wg_w[p * 8 + j];
        biasout[b * 32 + co] = s;
    }
}

// A_bf16[b][co][k], k = tap*16 + ci, tap = kd*9+kh*3+kw, zero for tap==27
__global__ void wgen_kernel(const float* __restrict__ h1,
                            const float* __restrict__ wg_w,
                            const float* __restrict__ wg_b,
                            short* __restrict__ A) {
    const int b  = blockIdx.y;
    const int id = blockIdx.x * 256 + threadIdx.x;  // [0, 32*16*28)
    const int tap  = id % 28;
    const int rest = id / 28;        // co*16 + ci
    const int ci   = rest & 15;
    const int co   = rest >> 4;
    float val = 0.f;
    if (tap < 27) {
        const int p = co * 432 + ci * 27 + tap;
        float s = wg_b[p];
        #pragma unroll
        for (int j = 0; j < 8; ++j) s += h1[b * 8 + j] * wg_w[p * 8 + j];
        val = s;
    }
    A[(b * 32 + co) * KPAD + tap * 16 + ci] = f2bf(val);
}

// stage one (dz, phys-hz) row of the x-patch: 2 ci planes x float4 of w.
__device__ __forceinline__ void stage_one(const float* __restrict__ x, char* xsb,
                                          int b, int cp, int w4,
                                          int dz, int phys, int zd, int zh) {
    float4 v0 = {0.f, 0.f, 0.f, 0.f};
    float4 v1 = {0.f, 0.f, 0.f, 0.f};
    if (zd >= 0 && zd < DD && zh >= 0 && zh < DD) {   // wave-uniform
        const size_t gbase =
            (((size_t)(b * CIN + 2 * cp) * DD + zd) * DD + zh) * DD + w4;
        v0 = *(const float4*)(x + gbase);
        v1 = *(const float4*)(x + gbase + (size_t)DD * DD * DD);
    }
    const int rb = ((dz * 6 + phys) * 66 + (w4 + 1)) * 32 + 4 * cp;
    *(unsigned*)(xsb + swz(rb))      = pack2bf(v0.x, v1.x);
    *(unsigned*)(xsb + swz(rb + 32)) = pack2bf(v0.y, v1.y);
    *(unsigned*)(xsb + swz(rb + 64)) = pack2bf(v0.z, v1.z);
    *(unsigned*)(xsb + swz(rb + 96)) = pack2bf(v0.w, v1.w);
}

// Implicit-GEMM conv via MFMA 16x16x32 bf16 — persistent 8-tile blocks.
// Block = 256 thr = 4 waves; fixes (b, d, h-half); loops 8 tiles over h0.
// A chunks 0..12 staged to LDS ONCE per block (conflict-free layout); the
// x-patch is a ROLLING hz-window (slot = (zh+1) mod 6): tiles 1..7 stage only
// the 12 new rows (vs 18). K-loop has NO global loads.
__global__ __launch_bounds__(256, 2) void conv_mfma_kernel(
        const float* __restrict__ x,
        const short* __restrict__ A,
        const float* __restrict__ bias,
        float* __restrict__ out) {
    __shared__ uint4 xs4[2376];            // 38016 B: [dz 3][slot 6][wz 66][ci 16]
    __shared__ uint4 als4[1664];           // 26624 B = 26 * 1024B (c 0..12, mt 0..1)
    char* xsb = (char*)xs4;
    char* alb = (char*)als4;

    const int t    = threadIdx.x;
    const int lane = t & 63;
    const int wave = t >> 6;
    const int n16  = lane & 15;
    const int q    = lane >> 4;

    // Persistent grid: 1024 blocks, 8 XCDs -> each XCD owns one sample b.
    const int lin   = blockIdx.x;                    // 0..1023
    const int o     = (lin & 7) * 128 + (lin >> 3);  // bijective
    const int b     = o >> 7;                        // 0..7
    const int rest  = o & 127;
    const int d     = rest >> 1;                     // 0..63
    const int hbase = (rest & 1) * 32;               // h0 = hbase + it*4

    const short* Ab = A + (size_t)(b * 32) * KPAD;

    // ---- stage A chunks 0..12 -> LDS once (1664 uint4 units, linear dest) ----
    #pragma unroll
    for (int i = 0; i < 7; ++i) {
        const int u = t + i * 256;
        if (u < 1664) {
            const int cm = u >> 6;
            const int c  = cm >> 1, mt = cm & 1;
            const int nn = (u >> 2) & 15, qs = u & 3;
            als4[u] = *(const uint4*)(Ab + (mt * 16 + nn) * KPAD + c * 32 + qs * 8);
        }
    }

    // ---- chunk 13 (taps 26,27; k>=432 already zero in A) per-thread regs ----
    short8 af13[2];
    af13[0] = *(const short8*)(Ab + n16 * KPAD + 13 * 32 + q * 8);
    af13[1] = *(const short8*)(Ab + (16 + n16) * KPAD + 13 * 32 + q * 8);

    // ---- zero the w-halo columns (wz=0,65) once; staging never writes them ----
    if (t < 72) {
        const int rowl = t >> 2;                 // 0..17
        const int wz   = ((t >> 1) & 1) * 65;    // 0 or 65
        const int half = t & 1;
        const uint4 z4 = {0u, 0u, 0u, 0u};
        *(uint4*)(xsb + swz((rowl * 66 + wz) * 32 + half * 16)) = z4;
    }

    const float bv0 = bias[b * 32 + n16];
    const float bv1 = bias[b * 32 + 16 + n16];

    // staging thread map: (ci-pair cp, row-half rhalf)
    const int tid16 = wave * 4 + q;      // 0..15
    const int cp    = tid16 & 7;         // ci = 2*cp, 2*cp+1
    const int rhalf = tid16 >> 3;        // 0/1
    const int w4    = n16 * 4;

    const int ci_base2 = (q & 1) * 16;   // byte offset of ci half
    const int qh       = q >> 1;
    const int aoff     = n16 * 64 + q * 16;   // lane's byte in a 1024B slot-group

    #pragma unroll 1
    for (int it = 0; it < 8; ++it) {
        const int h0 = hbase + it * 4;
        const int p  = h0 % 6;           // phys slot = (p + hz) mod 6 = (zh+1) mod 6

        __syncthreads();   // prev tile's LDS reads (or A-stage/halo-zero) done

        if (it == 0) {
            // full window: 18 rows, 9 per rhalf
            #pragma unroll
            for (int i = 0; i < 9; ++i) {
                const int rowl = rhalf * 9 + i;          // dz*6+hz
                const int dz = rowl / 6, hz = rowl % 6;
                int phys = p + hz; if (phys >= 6) phys -= 6;
                stage_one(x, xsb, b, cp, w4, dz, phys, d + dz - 1, h0 + hz - 1);
            }
        } else {
            // rolling: only hz 2..5 are new (zh = h0+1 .. h0+4), 12 rows
            #pragma unroll
            for (int i = 0; i < 6; ++i) {
                const int idx = rhalf * 6 + i;           // 0..11
                const int dz = idx >> 2, j = idx & 3;    // hz = 2+j
                int phys = p + 2 + j; if (phys >= 6) phys -= 6;
                stage_one(x, xsb, b, cp, w4, dz, phys, d + dz - 1, h0 + 1 + j);
            }
        }
        __syncthreads();

        // ---- K-loop: operand-swapped MFMA (x in A slot, weights in B slot) ----
        floatx4 acc[2][4];
        #pragma unroll
        for (int mt = 0; mt < 2; ++mt)
            #pragma unroll
            for (int nt = 0; nt < 4; ++nt) acc[mt][nt] = (floatx4){0.f, 0.f, 0.f, 0.f};

        __builtin_amdgcn_s_setprio(1);
        #pragma unroll
        for (int c = 0; c < 14; ++c) {
            int tap = 2 * c + qh;
            if (tap > 26) tap = 26;        // A zero for k>=432, x value irrelevant
            const int kd = tap / 9;
            const int r  = tap - kd * 9;
            const int kh = r / 3;
            const int kw = r - kh * 3;
            int prow = p + wave + kh; if (prow >= 6) prow -= 6;
            const int rowb = ((kd * 6 + prow) * 66 + kw) * 32 + ci_base2;
            const short8 a0 = (c < 13) ? *(const short8*)(alb + (c * 2) * 1024 + aoff)
                                       : af13[0];
            const short8 a1 = (c < 13) ? *(const short8*)(alb + (c * 2 + 1) * 1024 + aoff)
                                       : af13[1];
            #pragma unroll
            for (int nt = 0; nt < 4; ++nt) {
                const short8 xf = *(const short8*)(xsb + swz(rowb + (nt * 16 + n16) * 32));
                acc[0][nt] = __builtin_amdgcn_mfma_f32_16x16x32_bf16(
                                 xf, a0, acc[0][nt], 0, 0, 0);
                acc[1][nt] = __builtin_amdgcn_mfma_f32_16x16x32_bf16(
                                 xf, a1, acc[1][nt], 0, 0, 0);
            }
        }
        __builtin_amdgcn_s_setprio(0);

        // ---- epilogue: row=w=nt*16+q*4+reg, col=co=mt*16+n16 -> float4 stores ----
        const int hh = h0 + wave;
        #pragma unroll
        for (int mt = 0; mt < 2; ++mt) {
            const float bv = mt ? bv1 : bv0;
            #pragma unroll
            for (int nt = 0; nt < 4; ++nt) {
                floatx4 rr = acc[mt][nt];
                rr[0] += bv; rr[1] += bv; rr[2] += bv; rr[3] += bv;
                *(floatx4*)(out + (((size_t)(b * COUT + mt * 16 + n16) * DD + d) * DD + hh) * DD
                                 + nt * 16 + q * 4) = rr;
            }
        }
    }
}

extern "C" void kernel_launch(void* const* d_in, const int* in_sizes, int n_in,
                              void* d_out, int out_size, void* d_ws, size_t ws_size,
                              hipStream_t stream) {
    const float* x        = (const float*)d_in[0];
    const float* features = (const float*)d_in[1];
    const float* fc0_w    = (const float*)d_in[2];
    const float* fc0_b    = (const float*)d_in[3];
    const float* a0       = (const float*)d_in[4];
    const float* fc1_w    = (const float*)d_in[5];
    const float* fc1_b    = (const float*)d_in[6];
    const float* a1       = (const float*)d_in[7];
    const float* wg_w     = (const float*)d_in[8];
    const float* wg_b     = (const float*)d_in[9];

    float* ws    = (float*)d_ws;
    float* h1    = ws;                // 64 floats
    float* biasp = ws + 64;           // 256 floats
    short* A     = (short*)(ws + 320);  // 8*32*448 shorts

    hyper_kernel<<<1, 256, 0, stream>>>(features, fc0_w, fc0_b, a0,
                                        fc1_w, fc1_b, a1, wg_w, wg_b, h1, biasp);
    wgen_kernel<<<dim3(56, BB), 256, 0, stream>>>(h1, wg_w, wg_b, A);
    conv_mfma_kernel<<<dim3(1024), 256, 0, stream>>>(x, A, biasp, (float*)d_out);
}